// Round 1
// baseline (967.975 us; speedup 1.0000x reference)
//
#include <hip/hip_runtime.h>
#include <hip/hip_bf16.h>

#define USER_NUM 50000
#define ITEM_NUM 20000
#define NNODE    70000
#define DD       64

__device__ __forceinline__ float node_feat(const float* __restrict__ ue,
                                           const float* __restrict__ ie,
                                           int n, int d) {
    return (n < USER_NUM) ? ue[n * DD + d] : ie[(n - USER_NUM) * DD + d];
}

// One wave per edge; lane = feature dim. Fused lx and lx2 accumulation.
__global__ __launch_bounds__(256) void spmm_kernel(
    const float* __restrict__ ue, const float* __restrict__ ie,
    const int* __restrict__ erow, const int* __restrict__ ecol,
    const float* __restrict__ eval,
    float* __restrict__ lx, float* __restrict__ lx2, int E) {
    const int lane = threadIdx.x & 63;
    const int wave = (int)((blockIdx.x * blockDim.x + threadIdx.x) >> 6);
    const int nw   = (int)((gridDim.x * blockDim.x) >> 6);
    for (int e = wave; e < E; e += nw) {
        const int r = erow[e];
        const int c = ecol[e];
        const float v = eval[e];
        const float f = node_feat(ue, ie, c, lane);
        unsafeAtomicAdd(&lx [r * DD + lane], v * f);
        unsafeAtomicAdd(&lx2[r * DD + lane], v * f * f);
    }
}

// One wave per node: h = leaky_relu((lx+f)@Wg1 + bg1 + lx2@Wg2 + bg2)
__global__ __launch_bounds__(256) void transform_kernel(
    const float* __restrict__ ue, const float* __restrict__ ie,
    const float* __restrict__ lx, const float* __restrict__ lx2,
    const float* __restrict__ Wg1, const float* __restrict__ bg1,
    const float* __restrict__ Wg2, const float* __restrict__ bg2,
    float* __restrict__ h) {
    __shared__ float sW1[DD * DD];
    __shared__ float sW2[DD * DD];
    for (int i = threadIdx.x; i < DD * DD; i += 256) {
        sW1[i] = Wg1[i];
        sW2[i] = Wg2[i];
    }
    __syncthreads();
    const int lane = threadIdx.x & 63;
    const int wave = (int)((blockIdx.x * blockDim.x + threadIdx.x) >> 6);
    const int nw   = (int)((gridDim.x * blockDim.x) >> 6);
    const float bias1 = bg1[lane];
    const float bias2 = bg2[lane];
    for (int n = wave; n < NNODE; n += nw) {
        const float f  = node_feat(ue, ie, n, lane);
        const float a1 = lx[n * DD + lane] + f;
        const float a2 = lx2[n * DD + lane];
        float acc1 = bias1, acc2 = bias2;
#pragma unroll
        for (int k = 0; k < DD; ++k) {
            const float e1 = __shfl(a1, k);
            const float e2 = __shfl(a2, k);
            acc1 += e1 * sW1[k * DD + lane];
            acc2 += e2 * sW2[k * DD + lane];
        }
        const float x = acc1 + acc2;
        h[n * DD + lane] = (x > 0.f) ? x : 0.01f * x;
    }
}

// One wave per sample: gather [f_u, h_u, f_i, h_i] -> 3-layer MLP -> scalar.
__global__ __launch_bounds__(256) void mlp_kernel(
    const float* __restrict__ ue, const float* __restrict__ ie,
    const float* __restrict__ h,
    const float* __restrict__ W1, const float* __restrict__ b1,
    const float* __restrict__ W2, const float* __restrict__ b2,
    const float* __restrict__ W3, const float* __restrict__ b3,
    const int* __restrict__ uid, const int* __restrict__ iid,
    float* __restrict__ out, int B) {
    __shared__ float sEmb[4][256];
    __shared__ float sW2[DD * 32];
    __shared__ float sW3[32];
    for (int i = threadIdx.x; i < DD * 32; i += 256) sW2[i] = W2[i];
    if (threadIdx.x < 32) sW3[threadIdx.x] = W3[threadIdx.x];
    __syncthreads();
    const int lane = threadIdx.x & 63;
    const int w    = threadIdx.x >> 6;
    const int wave = (int)((blockIdx.x * blockDim.x + threadIdx.x) >> 6);
    const int nw   = (int)((gridDim.x * blockDim.x) >> 6);
    const float bias1 = b1[lane];
    const float bias2 = b2[lane & 31];
    const float w3v   = sW3[lane & 31];
    const float bias3 = b3[0];
    for (int s = wave; s < B; s += nw) {
        const int u  = uid[s];
        const int it = iid[s];
        sEmb[w][lane]        = ue[u * DD + lane];
        sEmb[w][64 + lane]   = h[u * DD + lane];
        sEmb[w][128 + lane]  = ie[it * DD + lane];
        sEmb[w][192 + lane]  = h[(USER_NUM + it) * DD + lane];
        // intra-wave LDS RAW: compiler inserts lgkmcnt wait (same-wave, in order)
        float acc = bias1;
#pragma unroll 8
        for (int k = 0; k < 256; ++k) {
            acc += sEmb[w][k] * W1[k * DD + lane];
        }
        const float o1 = (acc > 0.f) ? acc : 0.f;
        float acc2 = bias2;
#pragma unroll
        for (int k = 0; k < DD; ++k) {
            const float e = __shfl(o1, k);
            acc2 += e * sW2[k * 32 + (lane & 31)];
        }
        const float o2 = (acc2 > 0.f) ? acc2 : 0.f;
        float p = o2 * w3v;
        p += __shfl_xor(p, 1);
        p += __shfl_xor(p, 2);
        p += __shfl_xor(p, 4);
        p += __shfl_xor(p, 8);
        p += __shfl_xor(p, 16);
        if (lane == 0) out[s] = p + bias3;
    }
}

extern "C" void kernel_launch(void* const* d_in, const int* in_sizes, int n_in,
                              void* d_out, int out_size, void* d_ws, size_t ws_size,
                              hipStream_t stream) {
    const float* ue   = (const float*)d_in[0];
    const float* ie   = (const float*)d_in[1];
    const int*   erow = (const int*)d_in[2];
    const int*   ecol = (const int*)d_in[3];
    const float* evalp= (const float*)d_in[4];
    const float* Wg1  = (const float*)d_in[5];
    const float* bg1  = (const float*)d_in[6];
    const float* Wg2  = (const float*)d_in[7];
    const float* bg2  = (const float*)d_in[8];
    const float* W1   = (const float*)d_in[9];
    const float* b1   = (const float*)d_in[10];
    const float* W2   = (const float*)d_in[11];
    const float* b2   = (const float*)d_in[12];
    const float* W3   = (const float*)d_in[13];
    const float* b3   = (const float*)d_in[14];
    const int*   uid  = (const int*)d_in[15];
    const int*   iid  = (const int*)d_in[16];
    float* out = (float*)d_out;

    const int E = in_sizes[2];
    const int B = in_sizes[15];

    const size_t nd = (size_t)NNODE * DD;       // 4,480,000 floats
    float* lx  = (float*)d_ws;
    float* lx2 = lx + nd;
    float* h   = lx2 + nd;

    hipMemsetAsync(d_ws, 0, 2 * nd * sizeof(float), stream);

    spmm_kernel<<<4096, 256, 0, stream>>>(ue, ie, erow, ecol, evalp, lx, lx2, E);
    transform_kernel<<<1024, 256, 0, stream>>>(ue, ie, lx, lx2, Wg1, bg1, Wg2, bg2, h);
    mlp_kernel<<<1024, 256, 0, stream>>>(ue, ie, h, W1, b1, W2, b2, W3, b3,
                                         uid, iid, out, B);
}